// Round 1
// 307.504 us; speedup vs baseline: 1.0902x; 1.0902x over previous
//
#include <hip/hip_runtime.h>

// MultiCellLSTM: B=4096 chains, H=64, T=512, 3 cell types by t%4 (0,2,1,2).
// R4: operand-SWAPPED MFMA (D = W . hx^T, i.e. G transposed):
//  - A- and B-fragment lane layouts are symmetric (lane&15 = spatial,
//    lane>>4 = k-group), so whs/wix/hx/x fragment register CONTENTS are
//    unchanged from R3 -- only mfma argument order flips.
//  - D layout (col=lane&15=row, row=4q+r=gate-col) puts each lane's 4 cell
//    updates at 4 CONSECUTIVE h-columns of ONE batch-row: h write-back is
//    2x v_cvt_pk_bf16_f32 + one ds_write_b64 (was 4x RNE-twiddle + b16).
//  - bias C-input now per-lane {b[n], b[n+1], b[n+2], b[n+3]} (n=g*64+16w+4q).
//  - x reads grouped per 4-step macro step (b64+b32+u16, was 12x u16) and
//    prefetched one group ahead -> off the post-barrier critical path.
//  - per gate, the x-MFMA (register operands only) issues BEFORE the hx
//    MFMAs so it overlaps the a0/a1 ds_read_b128 latency.
// Carried from R3: 16 rows/block, 4 waves = 4 h-col slices, ONE barrier/step;
// bias as MFMA C-input; activation scale folded into weights
// (y = W'.x, act = rcp(1+exp2(y))); x buffers stride-padded conflict-free.
// Stale x2/x3 at off-phase steps are masked by zero weight columns.

typedef __attribute__((ext_vector_type(8))) short short8v;
typedef __attribute__((ext_vector_type(4))) float float4v;
typedef __attribute__((ext_vector_type(4))) unsigned short ushort4v;
typedef __attribute__((ext_vector_type(2))) unsigned int uint2v;

template <int N> struct IC { static constexpr int value = N; };

#define AST 72   // shorts per A row: 64 hx + 8 pad; 16B-aligned frags (144c+16q)
#define XS1 516  // x1 row stride (shorts): dword-stride 258 mod 32 = 2 -> conflict-free
#define XS2 260
#define XS3 132

#if __has_builtin(__builtin_amdgcn_exp2f)
#define EXP2F(x) __builtin_amdgcn_exp2f(x)
#else
#define EXP2F(x) exp2f(x)
#endif
#if __has_builtin(__builtin_amdgcn_rcpf)
#define RCPF(x) __builtin_amdgcn_rcpf(x)
#else
#define RCPF(x) (1.0f / (x))
#endif

#define NL2E -1.4426950408889634f   // -log2(e)
#define NL2E2 -2.8853900817779268f  // -2*log2(e)

__device__ __forceinline__ short f2bf(float f) {
  union { float f; unsigned u; } v; v.f = f;
  unsigned r = v.u + 0x7FFFu + ((v.u >> 16) & 1u);  // RNE
  return (short)(r >> 16);
}
__device__ __forceinline__ float bf2f(short h) {
  union { float f; unsigned u; } v;
  v.u = ((unsigned)(unsigned short)h) << 16;
  return v.f;
}
// pack two f32 -> two bf16 (RNE, MODE.round default) in one instr
__device__ __forceinline__ unsigned cvt_pk_bf16(float lo, float hi) {
  unsigned r;
  asm("v_cvt_pk_bf16_f32 %0, %1, %2" : "=v"(r) : "v"(lo), "v"(hi));
  return r;
}
// act on pre-scaled y: sigmoid(x) = rcp(1+exp2(y)), y = x*NL2E
__device__ __forceinline__ float rcp1p(float y) {
  return RCPF(1.0f + EXP2F(y));
}
__device__ __forceinline__ float fsig(float x) { return rcp1p(x * NL2E); }
__device__ __forceinline__ float ftanh(float x) {
  return __builtin_fmaf(2.0f, rcp1p(x * NL2E2), -1.0f);
}

__global__ __launch_bounds__(256, 1) void mlstm_kernel(
    const float* __restrict__ x1, const float* __restrict__ x2,
    const float* __restrict__ x3,
    const float* __restrict__ Wi3, const float* __restrict__ Wh3,
    const float* __restrict__ bi3, const float* __restrict__ bh3,
    const float* __restrict__ Wi2, const float* __restrict__ Wh2,
    const float* __restrict__ bi2, const float* __restrict__ bh2,
    const float* __restrict__ Wi1, const float* __restrict__ Wh1,
    const float* __restrict__ bi1, const float* __restrict__ bh1,
    const float* __restrict__ Wout, const float* __restrict__ bout,
    float* __restrict__ out) {
  __shared__ __attribute__((aligned(16))) short Ab0[16 * AST];
  __shared__ __attribute__((aligned(16))) short Ab1[16 * AST];
  __shared__ __attribute__((aligned(16))) short x1b[16 * XS1];
  __shared__ __attribute__((aligned(16))) short x2b[16 * XS2];
  __shared__ __attribute__((aligned(16))) short x3b[16 * XS3];

  const int tid = threadIdx.x;  // 0..255
  const int w = tid >> 6;       // wave = h-col slice 0..3
  const int lane = tid & 63;
  const int q = lane >> 4;
  const int c = lane & 15;
  const int R0 = blockIdx.x << 4;

  // ---- preload x into LDS as bf16 (padded strides) ----
  for (int idx = tid; idx < 16 * 512; idx += 256) {
    int m = idx >> 9, t = idx & 511;
    x1b[m * XS1 + t] = f2bf(x1[(size_t)(R0 + m) * 512 + t]);
  }
  for (int idx = tid; idx < 16 * 256; idx += 256) {
    int m = idx >> 8, t = idx & 255;
    x2b[m * XS2 + t] = f2bf(x2[(size_t)(R0 + m) * 256 + t]);
  }
  for (int idx = tid; idx < 16 * 128; idx += 256) {
    int m = idx >> 7, t = idx & 127;
    x3b[m * XS3 + t] = f2bf(x3[(size_t)(R0 + m) * 128 + t]);
  }
  // ---- A buffers: hx(t=0) = 0 ----
  for (int idx = tid; idx < 16 * AST; idx += 256) {
    Ab0[idx] = 0;
    Ab1[idx] = 0;
  }

  // ---- pack scaled weight fragments (per wave: tiles g=0..3) ----
  // whs[ty][g][kf]: lane(q,c) elem j = s_g * Wh[g*64+16w+c][kf*32+q*8+j]
  //   (same registers serve as the SWAPPED-mfma A operand: A[m=c][k=8q+j])
  // wix[ty][g]    : k = 8q+j -> q==0,j<3: s_g * Wi[n][j], else 0
  // bias4[ty][g]  : D-layout C-input: elem r = s_g*(bi+bh)[g*64+16w+4q+r]
  short8v whs[3][4][2];
  short8v wix[3][4];
  float4v bias4[3][4];
  {
    const float* WhA[3] = {Wh3, Wh2, Wh1};
    const float* WiA[3] = {Wi3, Wi2, Wi1};
    const float* biA[3] = {bi3, bi2, bi1};
    const float* bhA[3] = {bh3, bh2, bh1};
    const int wdt[3] = {3, 2, 1};
#pragma unroll
    for (int ty = 0; ty < 3; ++ty) {
#pragma unroll
      for (int g = 0; g < 4; ++g) {
        const float sg = (g == 2) ? NL2E2 : NL2E;
        const int n = g * 64 + 16 * w + c;
#pragma unroll
        for (int kf = 0; kf < 2; ++kf) {
          short8v v;
#pragma unroll
          for (int j = 0; j < 8; ++j)
            v[j] = f2bf(sg * WhA[ty][n * 64 + kf * 32 + q * 8 + j]);
          whs[ty][g][kf] = v;
        }
        short8v v2 = {0, 0, 0, 0, 0, 0, 0, 0};
        if (q == 0) {
#pragma unroll
          for (int j = 0; j < 3; ++j)
            if (j < wdt[ty]) v2[j] = f2bf(sg * WiA[ty][n * wdt[ty] + j]);
        }
        wix[ty][g] = v2;
        float4v bv;
#pragma unroll
        for (int r = 0; r < 4; ++r) {
          const int nd = g * 64 + 16 * w + 4 * q + r;  // D-row = gate col
          bv[r] = sg * (biA[ty][nd] + bhA[ty][nd]);
        }
        bias4[ty][g] = bv;
      }
    }
  }

  // addressing
  const int afo = c * AST + q * 8;          // hx B-frag base: n=c(row), k=q*8+j
  const int hwo = c * AST + 16 * w + 4 * q; // h write: row c, cols 16w+4q+r (b64)
  const int x1o = c * XS1;                  // x row = c (broadcast across q)
  const int x2o = c * XS2;
  const int x3o = c * XS3;

  __syncthreads();

  float cx[4] = {0.f, 0.f, 0.f, 0.f};  // cell state: row c, hcol 16w+4q+r

  auto stepf = [&](auto tyc, auto sc, const short* rbuf, short* wbuf,
                   ushort4v xav, unsigned xbv, unsigned short xcv) {
    constexpr int TY = decltype(tyc)::value;
    constexpr int S = decltype(sc)::value;
    // x(t) B-frag row values for batch-row c: only k=0..2 of wix nonzero;
    // stale x2/x3 (and q>0 lanes) are multiplied by zero weights.
    short x1s = (short)xav[S];
    short x2s = (short)((S < 2) ? (xbv & 0xFFFFu) : (xbv >> 16));
    short8v a2 = {x1s, x2s, (short)xcv, 0, 0, 0, 0, 0};
    short8v a0 = *(const short8v*)(rbuf + afo);
    short8v a1 = *(const short8v*)(rbuf + afo + 32);

    float4v acc[4];
#pragma unroll
    for (int g = 0; g < 4; ++g) {
      float4v z = bias4[TY][g];
      // x-MFMA first: register operands, overlaps a0/a1 LDS latency
      z = __builtin_amdgcn_mfma_f32_16x16x32_bf16(wix[TY][g], a2, z, 0, 0, 0);
      z = __builtin_amdgcn_mfma_f32_16x16x32_bf16(whs[TY][g][0], a0, z, 0, 0, 0);
      z = __builtin_amdgcn_mfma_f32_16x16x32_bf16(whs[TY][g][1], a1, z, 0, 0, 0);
      acc[g] = z;  // acc[g][r] = gate g, row c, hcol 16w+4q+r
    }

    float h[4];
#pragma unroll
    for (int r = 0; r < 4; ++r) {
      float si = rcp1p(acc[0][r]);                              // sigmoid(i)
      float sf = rcp1p(acc[1][r]);                              // sigmoid(f)
      float tg = __builtin_fmaf(2.0f, rcp1p(acc[2][r]), -1.0f); // tanh(g)
      float so = rcp1p(acc[3][r]);                              // sigmoid(o)
      float ncx = __builtin_fmaf(sf, cx[r], si * tg);
      cx[r] = ncx;
      h[r] = so * ftanh(ncx);
    }
    uint2v pk;
    pk[0] = cvt_pk_bf16(h[0], h[1]);
    pk[1] = cvt_pk_bf16(h[2], h[3]);
    *(uint2v*)(wbuf + hwo) = pk;  // one ds_write_b64, ~2-way banked
    __syncthreads();
  };

  // x for group t4=0
  ushort4v xa = *(const ushort4v*)(x1b + x1o);
  unsigned xb = *(const unsigned*)(x2b + x2o);
  unsigned short xc = (unsigned short)x3b[x3o];

  // t%4 -> type: 0->0, 1->2, 2->1, 3->2
  for (int t4 = 0; t4 < 512; t4 += 4) {
    ushort4v xav = xa;
    unsigned xbv = xb;
    unsigned short xcv = xc;
    stepf(IC<0>{}, IC<0>{}, Ab0, Ab1, xav, xbv, xcv);
    // prefetch next group's x (last iter reads land in the pad region: safe,
    // values never consumed)
    xa = *(const ushort4v*)(x1b + x1o + t4 + 4);
    xb = *(const unsigned*)(x2b + x2o + ((t4 + 4) >> 1));
    xc = (unsigned short)x3b[x3o + ((t4 + 4) >> 2)];
    stepf(IC<2>{}, IC<1>{}, Ab1, Ab0, xav, xbv, xcv);
    stepf(IC<1>{}, IC<2>{}, Ab0, Ab1, xav, xbv, xcv);
    stepf(IC<2>{}, IC<3>{}, Ab1, Ab0, xav, xbv, xcv);
  }
  // final hx (after 512 steps) is in Ab0

  if (tid < 16) {
    float s = bout[0];
    const short* hr = Ab0 + tid * AST;
#pragma unroll
    for (int k = 0; k < 64; ++k)
      s = __builtin_fmaf(bf2f(hr[k]), Wout[k], s);
    out[R0 + tid] = fsig(s);
  }
}

extern "C" void kernel_launch(void* const* d_in, const int* in_sizes, int n_in,
                              void* d_out, int out_size, void* d_ws,
                              size_t ws_size, hipStream_t stream) {
  const float* x1 = (const float*)d_in[0];
  const float* x2 = (const float*)d_in[1];
  const float* x3 = (const float*)d_in[2];
  const float* Wi3 = (const float*)d_in[3];
  const float* Wh3 = (const float*)d_in[4];
  const float* bi3 = (const float*)d_in[5];
  const float* bh3 = (const float*)d_in[6];
  const float* Wi2 = (const float*)d_in[7];
  const float* Wh2 = (const float*)d_in[8];
  const float* bi2 = (const float*)d_in[9];
  const float* bh2 = (const float*)d_in[10];
  const float* Wi1 = (const float*)d_in[11];
  const float* Wh1 = (const float*)d_in[12];
  const float* bi1 = (const float*)d_in[13];
  const float* bh1 = (const float*)d_in[14];
  const float* Wout = (const float*)d_in[15];
  const float* bout = (const float*)d_in[16];
  float* out = (float*)d_out;

  hipLaunchKernelGGL(mlstm_kernel, dim3(256), dim3(256), 0, stream,
                     x1, x2, x3, Wi3, Wh3, bi3, bh3, Wi2, Wh2, bi2, bh2,
                     Wi1, Wh1, bi1, bh1, Wout, bout, out);
}